// Round 3
// baseline (472.574 us; speedup 1.0000x reference)
//
#include <hip/hip_runtime.h>
#include <hip/hip_bf16.h>
#include <cmath>

typedef __bf16 bf16x8 __attribute__((ext_vector_type(8)));
typedef __bf16 bf16x4 __attribute__((ext_vector_type(4)));
typedef float f32x4 __attribute__((ext_vector_type(4)));

#define GLOBAL_AS __attribute__((address_space(1)))
#define LDS_AS __attribute__((address_space(3)))

__device__ __forceinline__ void async_copy16(const void* g, void* l) {
    __builtin_amdgcn_global_load_lds((const GLOBAL_AS void*)g, (LDS_AS void*)l, 16, 0, 0);
}

// dims (hardcoded)
#define BB 8
#define SS 4096
#define EE 768
#define SKK 2048

// ---------------------------------------------------------------------------
// SEQ_idxes may be int64 or int32. As int32 words, int64 layout =
// [f0_lo, f0_hi(=0), ...]; int32 = [f0, s0(>=2049), ...]. seq[1]==0 <=> int64.
__device__ inline int get_first(const int* __restrict__ seq, int b) {
    int stride = (seq[1] == 0) ? 4 : 2;
    return seq[b * stride];
}

// ---------------------------------------------------------------------------
__global__ __launch_bounds__(256) void cast_f32_bf16(const float* __restrict__ in,
                                                     __bf16* __restrict__ out, int n4) {
    int i = blockIdx.x * 256 + threadIdx.x;
    if (i >= n4) return;
    float4 v = ((const float4*)in)[i];
    bf16x4 o;
    o[0] = (__bf16)v.x; o[1] = (__bf16)v.y; o[2] = (__bf16)v.z; o[3] = (__bf16)v.w;
    ((bf16x4*)out)[i] = o;
}

__global__ __launch_bounds__(256) void cast3_f32_bf16(
    const float* __restrict__ a, const float* __restrict__ b, const float* __restrict__ c,
    __bf16* __restrict__ oa, __bf16* __restrict__ ob, __bf16* __restrict__ oc, int n4) {
    int i = blockIdx.x * 256 + threadIdx.x;
    if (i >= n4) return;
    const float* in = (blockIdx.y == 0) ? a : (blockIdx.y == 1) ? b : c;
    __bf16* out = (blockIdx.y == 0) ? oa : (blockIdx.y == 1) ? ob : oc;
    float4 v = ((const float4*)in)[i];
    bf16x4 o;
    o[0] = (__bf16)v.x; o[1] = (__bf16)v.y; o[2] = (__bf16)v.z; o[3] = (__bf16)v.w;
    ((bf16x4*)out)[i] = o;
}

__global__ __launch_bounds__(256) void zero_f32(float* __restrict__ p, int n4) {
    int i = blockIdx.x * 256 + threadIdx.x;
    if (i < n4) ((f32x4*)p)[i] = f32x4{0.f, 0.f, 0.f, 0.f};
}

// ---------------------------------------------------------------------------
// Core 128x128 tile, BK=64, 256 thr = 4 waves (2x2), wave = 4x4 of 16x16x32.
// Staging via global_load_lds w=16; XOR-swizzled LDS (on global source index,
// dest is wave-uniform base + lane*16): slot s holds (row=s>>3, c8=(s&7)^(row&7)).
// Frag reads 2-way bank aliased only (free, m136). Bank conflicts measured 0.
__device__ __forceinline__ void gemm_core(
    const __bf16* __restrict__ A0, int lda,
    const __bf16* __restrict__ B0, int ldb, int K,
    char* As, char* Bs, f32x4 (&acc)[4][4]) {
    int tid = threadIdx.x;
    int lane = tid & 63, wid = tid >> 6;
    int waveM = (wid & 1) << 6, waveN = (wid >> 1) << 6;
    int quad = lane >> 4, l16 = lane & 15;
    int r0 = tid >> 3;
    int c8 = (tid & 7) ^ (r0 & 7);
    const __bf16* Ag = A0 + (long)r0 * lda + c8 * 8;
    const __bf16* Bg = B0 + (long)r0 * ldb + c8 * 8;
#pragma unroll
    for (int i = 0; i < 4; ++i)
#pragma unroll
        for (int j = 0; j < 4; ++j) acc[i][j] = f32x4{0.f, 0.f, 0.f, 0.f};
    int xorv = (l16 & 7) << 4;

    for (int k0 = 0; k0 < K; k0 += 64) {
        __syncthreads();  // prior reads (this item or previous item) done
#pragma unroll
        for (int r = 0; r < 4; ++r) {
            async_copy16(Ag + (long)(r * 32) * lda + k0, As + (tid + r * 256) * 16);
            async_copy16(Bg + (long)(r * 32) * ldb + k0, Bs + (tid + r * 256) * 16);
        }
        __syncthreads();  // drains vmcnt before use
#pragma unroll
        for (int s = 0; s < 2; ++s) {
            bf16x8 af[4], bfr[4];
#pragma unroll
            for (int i = 0; i < 4; ++i) {
                int chunk = (((s << 2) + quad) << 4) ^ xorv;
                af[i]  = *(const bf16x8*)(As + (waveM + i * 16 + l16) * 128 + chunk);
                bfr[i] = *(const bf16x8*)(Bs + (waveN + i * 16 + l16) * 128 + chunk);
            }
#pragma unroll
            for (int i = 0; i < 4; ++i)
#pragma unroll
                for (int j = 0; j < 4; ++j)
                    acc[i][j] = __builtin_amdgcn_mfma_f32_16x16x32_bf16(af[i], bfr[j], acc[i][j], 0, 0, 0);
        }
    }
}

// C/D frag: col = l16 (n), row = quad*4 + reg (m). [m89-verified]

// ---------------------------------------------------------------------------
// Fused Q/K/V projection, persistent work-queue.
// items: [0,1536)       Q: x=id%32 (m-tile), y=(id/32)%6 (n-tile), z=id/192
//        [1536,2304)    K: rel=id-1536: x=rel%16, y=(rel/16)%6, z=rel/96
//        [2304,3072)    V: same decode, transposed store to VT
__global__ __launch_bounds__(256) void proj_qkv(
    const __bf16* __restrict__ ebd,
    const __bf16* __restrict__ wq, const __bf16* __restrict__ wk, const __bf16* __restrict__ wv,
    const float* __restrict__ bq, const float* __restrict__ bk, const float* __restrict__ bv,
    __bf16* __restrict__ Qb, __bf16* __restrict__ Kb, __bf16* __restrict__ VT,
    const int* __restrict__ seq, int* __restrict__ ctr) {
    __shared__ char As[16384];
    __shared__ char Bs[16384];
    __shared__ int s_id;
    int tid = threadIdx.x;
    int lane = tid & 63, wid = tid >> 6;
    int waveM = (wid & 1) << 6, waveN = (wid >> 1) << 6;
    int quad = lane >> 4, l16 = lane & 15;

    for (;;) {
        __syncthreads();
        if (tid == 0) s_id = atomicAdd(ctr, 1);
        __syncthreads();
        int id = s_id;
        if (id >= 3072) return;

        int which, m0, n0, z;
        if (id < 1536) {
            which = 0; m0 = (id & 31) << 7; n0 = ((id >> 5) % 6) << 7; z = id / 192;
        } else {
            int rel = id - 1536;
            which = 1 + rel / 768; rel %= 768;
            m0 = (rel & 15) << 7; n0 = ((rel >> 4) % 6) << 7; z = rel / 96;
            if (m0 >= get_first(seq, z)) continue;
        }
        const __bf16* W = (which == 0) ? wq : (which == 1) ? wk : wv;
        const float* bias = (which == 0) ? bq : (which == 1) ? bk : bv;

        f32x4 acc[4][4];
        gemm_core(ebd + (long)z * SS * EE + (long)m0 * EE, EE, W + (long)n0 * EE, EE,
                  EE, As, Bs, acc);

        if (which == 2) {  // transposed store: VT[e][k-row]
            __bf16* C = VT + (long)z * EE * SKK;
#pragma unroll
            for (int i = 0; i < 4; ++i) {
                int rowb = m0 + waveM + i * 16 + quad * 4;
#pragma unroll
                for (int j = 0; j < 4; ++j) {
                    int col = n0 + waveN + j * 16 + l16;
                    float bv_ = bias[col];
                    bf16x4 o;
#pragma unroll
                    for (int r = 0; r < 4; ++r) o[r] = (__bf16)(acc[i][j][r] + bv_);
                    *(bf16x4*)&C[(long)col * SKK + rowb] = o;  // 8B aligned
                }
            }
        } else {
            __bf16* C = (which == 0) ? Qb + (long)z * SS * EE : Kb + (long)z * SKK * EE;
#pragma unroll
            for (int i = 0; i < 4; ++i) {
                int rowb = m0 + waveM + i * 16 + quad * 4;
#pragma unroll
                for (int j = 0; j < 4; ++j) {
                    int col = n0 + waveN + j * 16 + l16;
                    float bv_ = bias[col];
#pragma unroll
                    for (int r = 0; r < 4; ++r)
                        C[(long)(rowb + r) * EE + col] = (__bf16)(acc[i][j][r] + bv_);
                }
            }
        }
    }
}

// ---------------------------------------------------------------------------
// Scores: P = exp2(cs * Q K^T) masked to [1,first), bf16 + atomic rowsum.
// items: 4096 = 32 q-tiles x 16 n-tiles x 8 z
__global__ __launch_bounds__(256) void scores_k(
    const __bf16* __restrict__ Qb, const __bf16* __restrict__ Kb,
    __bf16* __restrict__ Pb, const int* __restrict__ seq,
    float* __restrict__ rowsum, int* __restrict__ ctr) {
    __shared__ char As[16384];
    __shared__ char Bs[16384];
    __shared__ int s_id;
    int tid = threadIdx.x;
    int lane = tid & 63, wid = tid >> 6;
    int waveM = (wid & 1) << 6, waveN = (wid >> 1) << 6;
    int quad = lane >> 4, l16 = lane & 15;
    const float cs = 1.44269504088896f / 27.712812921102035f;  // log2(e)/sqrt(768)

    for (;;) {
        __syncthreads();
        if (tid == 0) s_id = atomicAdd(ctr, 1);
        __syncthreads();
        int id = s_id;
        if (id >= 4096) return;
        int m0 = (id & 31) << 7, n0 = ((id >> 5) & 15) << 7, z = id >> 9;
        int first = get_first(seq, z);
        if (n0 >= first) continue;

        f32x4 acc[4][4];
        gemm_core(Qb + (long)z * SS * EE + (long)m0 * EE, EE,
                  Kb + (long)z * SKK * EE + (long)n0 * EE, EE, EE, As, Bs, acc);

        __bf16* C = Pb + (long)z * SS * SKK;
        float* rs = rowsum + (long)z * SS;
#pragma unroll
        for (int i = 0; i < 4; ++i) {
            int rowb = m0 + waveM + i * 16 + quad * 4;
            float sum[4] = {0.f, 0.f, 0.f, 0.f};
#pragma unroll
            for (int j = 0; j < 4; ++j) {
                int col = n0 + waveN + j * 16 + l16;
                bool valid = (col >= 1) && (col < first);
#pragma unroll
                for (int r = 0; r < 4; ++r) {
                    float e = valid ? exp2f(acc[i][j][r] * cs) : 0.0f;
                    __bf16 pb = (__bf16)e;
                    C[(long)(rowb + r) * SKK + col] = pb;
                    sum[r] += (float)pb;  // sum bf16-rounded value (consistent w/ PV)
                }
            }
#pragma unroll
            for (int r = 0; r < 4; ++r) {
                float v = sum[r];
                v += __shfl_xor(v, 8); v += __shfl_xor(v, 4);
                v += __shfl_xor(v, 2); v += __shfl_xor(v, 1);
                if (l16 == 0) atomicAdd(&rs[rowb + r], v);
            }
        }
    }
}

// ---------------------------------------------------------------------------
// PV: out = (P @ VT^T) / rowsum, fp32.  items: 1536 = 32 q x 6 e x 8 z.
// K = roundup64(first) per z -> heavily z-dependent: the work-queue is what
// balances this (static grid showed 17% occupancy from the long-batch tail).
__global__ __launch_bounds__(256) void pv_k(
    const __bf16* __restrict__ Pb, const __bf16* __restrict__ VT,
    float* __restrict__ out, const float* __restrict__ rowsum,
    const int* __restrict__ seq, int* __restrict__ ctr) {
    __shared__ char As[16384];
    __shared__ char Bs[16384];
    __shared__ int s_id;
    int tid = threadIdx.x;
    int lane = tid & 63, wid = tid >> 6;
    int waveM = (wid & 1) << 6, waveN = (wid >> 1) << 6;
    int quad = lane >> 4, l16 = lane & 15;

    for (;;) {
        __syncthreads();
        if (tid == 0) s_id = atomicAdd(ctr, 1);
        __syncthreads();
        int id = s_id;
        if (id >= 1536) return;
        int m0 = (id & 31) << 7;
        int t = id >> 5;
        int n0 = (t % 6) << 7, z = t / 6;
        int K = (get_first(seq, z) + 63) & ~63;

        f32x4 acc[4][4];
        gemm_core(Pb + (long)z * SS * SKK + (long)m0 * SKK, SKK,
                  VT + (long)z * EE * SKK + (long)n0 * SKK, SKK, K, As, Bs, acc);

        float* C = out + (long)z * SS * EE;
        const float* rs = rowsum + (long)z * SS;
#pragma unroll
        for (int i = 0; i < 4; ++i) {
            int rowb = m0 + waveM + i * 16 + quad * 4;
            float inv[4];
#pragma unroll
            for (int r = 0; r < 4; ++r) inv[r] = 1.0f / rs[rowb + r];
#pragma unroll
            for (int j = 0; j < 4; ++j) {
                int col = n0 + waveN + j * 16 + l16;
#pragma unroll
                for (int r = 0; r < 4; ++r)
                    C[(long)(rowb + r) * EE + col] = acc[i][j][r] * inv[r];
            }
        }
    }
}

// ---------------------------------------------------------------------------
extern "C" void kernel_launch(void* const* d_in, const int* in_sizes, int n_in,
                              void* d_out, int out_size, void* d_ws, size_t ws_size,
                              hipStream_t stream) {
    const int B = BB, S = SS, E = EE, SK = SKK;
    const float* ebd  = (const float*)d_in[0];
    const int*   seq  = (const int*)d_in[1];
    const float* Wq_w = (const float*)d_in[2];
    const float* Wq_b = (const float*)d_in[3];
    const float* Wk_w = (const float*)d_in[4];
    const float* Wk_b = (const float*)d_in[5];
    const float* Wv_w = (const float*)d_in[6];
    const float* Wv_b = (const float*)d_in[7];
    float* out = (float*)d_out;

    char* p = (char*)d_ws;
    __bf16* ebd_bf = (__bf16*)p; p += (size_t)B * S * E * 2;   // 50.3 MB
    __bf16* wq = (__bf16*)p;     p += (size_t)E * E * 2;
    __bf16* wk = (__bf16*)p;     p += (size_t)E * E * 2;
    __bf16* wv = (__bf16*)p;     p += (size_t)E * E * 2;
    __bf16* Qb = (__bf16*)p;     p += (size_t)B * S * E * 2;   // 50.3 MB
    __bf16* Kb = (__bf16*)p;     p += (size_t)B * SK * E * 2;  // 25.2 MB
    __bf16* VT = (__bf16*)p;     p += (size_t)B * E * SK * 2;  // 25.2 MB  V^T [b][e][k]
    __bf16* Pb = (__bf16*)p;     p += (size_t)B * S * SK * 2;  // 134.2 MB
    float* rowsum = (float*)p;   p += (size_t)B * S * 4;       // 128 KB
    int* ctrs = (int*)p;         p += 256;                     // 3 work-queue counters

    // zero rowsum + counters (ws is re-poisoned 0xAA before every call)
    zero_f32<<<(B * S / 4 + 64 + 255) / 256, 256, 0, stream>>>(rowsum, B * S / 4 + 64);
    cast_f32_bf16<<<(B * S * E / 4 + 255) / 256, 256, 0, stream>>>(ebd, ebd_bf, B * S * E / 4);
    cast3_f32_bf16<<<dim3((E * E / 4 + 255) / 256, 3), 256, 0, stream>>>(
        Wq_w, Wk_w, Wv_w, wq, wk, wv, E * E / 4);

    const int NB = 1280;  // 5 blocks/CU (32 KB LDS, 92 VGPR)
    proj_qkv<<<NB, 256, 0, stream>>>(ebd_bf, wq, wk, wv, Wq_b, Wk_b, Wv_b,
                                     Qb, Kb, VT, seq, ctrs + 0);
    scores_k<<<NB, 256, 0, stream>>>(Qb, Kb, Pb, seq, rowsum, ctrs + 1);
    pv_k<<<NB, 256, 0, stream>>>(Pb, VT, out, rowsum, seq, ctrs + 2);
}